// Round 4
// baseline (13722.656 us; speedup 1.0000x reference)
//
#include <hip/hip_runtime.h>

typedef __attribute__((ext_vector_type(8))) short short8;
typedef __attribute__((ext_vector_type(4))) float floatx4;

#define BQ 16
#define LQ 512
#define DM 1024
#define DPROJ 4384
#define RAWC 2336
#define KD 2048
#define NWG 128          // scan workgroups
#define NTHR 512         // threads per scan wg (8 waves)
#define AWG 73           // wgs running phase A: 73 x 32 cols = 2336

#define RAWP_WSTRIDE 37376    // 16*2336 u64
#define RAWP_SLOT   299008    // 8*16*2336 u64
#define TAG_SLOT     16384    // 16*1024 u64
#define MSUM_SLOT      512    // 16*32 u64

__device__ __forceinline__ float siluf(float x) { return x / (1.f + __expf(-x)); }
__device__ __forceinline__ float softplusf(float x) { return (x > 20.f) ? x : log1pf(__expf(x)); }
__device__ __forceinline__ unsigned short f2bf(float f) {
    union { float f; unsigned u; } v; v.f = f;
    unsigned r = v.u + 0x7FFFu + ((v.u >> 16) & 1u);
    return (unsigned short)(r >> 16);
}
__device__ __forceinline__ unsigned long long ld64(const unsigned long long* p) {
    return __hip_atomic_load(p, __ATOMIC_RELAXED, __HIP_MEMORY_SCOPE_AGENT);
}
__device__ __forceinline__ void st64(unsigned long long* p, unsigned long long v) {
    __hip_atomic_store(p, v, __ATOMIC_RELAXED, __HIP_MEMORY_SCOPE_AGENT);
}
__device__ __forceinline__ unsigned long long packf(float f, unsigned e) {
    union { float f; unsigned u; } v; v.f = f;
    return ((unsigned long long)e << 32) | v.u;
}
__device__ __forceinline__ unsigned long long packu(unsigned payload, unsigned e) {
    return ((unsigned long long)e << 32) | payload;
}
__device__ __forceinline__ float lof(unsigned long long w) {
    union { unsigned u; float f; } v; v.u = (unsigned)w; return v.f;
}
__device__ __forceinline__ unsigned hie(unsigned long long w) { return (unsigned)(w >> 32); }

// ---------------- fp32 -> bf16 conversion ----------------
__global__ void cvt_bf16_kernel(const float* __restrict__ s, unsigned short* __restrict__ d, int n) {
    int i = blockIdx.x * 256 + threadIdx.x;
    if (i < n) d[i] = f2bf(s[i]);
}

// ---------------- pack [W_rxbc|W_rdt|W_out] -> bf16 [3360][2048] ----------------
__global__ void pack_weights_kernel(const float* __restrict__ rxbc, const float* __restrict__ rdt,
                                    const float* __restrict__ wout, unsigned short* __restrict__ wall) {
    long i = (long)blockIdx.x * 256 + threadIdx.x;
    if (i >= 3360L * KD) return;
    int c = (int)(i >> 11), k = (int)(i & 2047);
    const float* src = (c < 2304) ? rxbc + (long)c * KD + k
                     : (c < 2336) ? rdt + (long)(c - 2304) * KD + k
                     :              wout + (long)(c - 2336) * KD + k;
    wall[i] = f2bf(*src);
}

// ---------------- zero init (NO hipMemsetAsync: graph-capture tripwire) ----------
__global__ void setup_zero_kernel(unsigned* __restrict__ base, long n) {
    long i = (long)blockIdx.x * 256 + threadIdx.x;
    for (; i < n; i += (long)gridDim.x * 256) base[i] = 0u;
}

// ---------------- in_proj GEMM: 128x32 blocks ----------
__global__ __launch_bounds__(256) void gemm_inproj_kernel(const short* __restrict__ A,
                                                          const short* __restrict__ Bw,
                                                          float* __restrict__ C) {
    const int lane = threadIdx.x & 63, wave = threadIdx.x >> 6;
    const int row = lane & 15, q = lane >> 4;
    const long m0 = (long)blockIdx.x * 128 + wave * 16;
    const long n0 = (long)blockIdx.y * 32;
    const short* ap0 = A + (m0 + row) * DM + q * 8;
    const short* ap1 = ap0 + 64 * DM;
    const short* bp0 = Bw + (n0 + row) * DM + q * 8;
    const short* bp1 = bp0 + 16 * DM;
    floatx4 acc00 = {0.f,0.f,0.f,0.f}, acc01 = {0.f,0.f,0.f,0.f};
    floatx4 acc10 = {0.f,0.f,0.f,0.f}, acc11 = {0.f,0.f,0.f,0.f};
    for (int k = 0; k < DM; k += 32) {
        short8 a0 = *(const short8*)(ap0 + k);
        short8 a1 = *(const short8*)(ap1 + k);
        short8 b0 = *(const short8*)(bp0 + k);
        short8 b1 = *(const short8*)(bp1 + k);
        acc00 = __builtin_amdgcn_mfma_f32_16x16x32_bf16(a0, b0, acc00, 0, 0, 0);
        acc01 = __builtin_amdgcn_mfma_f32_16x16x32_bf16(a0, b1, acc01, 0, 0, 0);
        acc10 = __builtin_amdgcn_mfma_f32_16x16x32_bf16(a1, b0, acc10, 0, 0, 0);
        acc11 = __builtin_amdgcn_mfma_f32_16x16x32_bf16(a1, b1, acc11, 0, 0, 0);
    }
    float* cp0 = C + (m0 + q * 4) * DPROJ + n0 + row;
    float* cp1 = cp0 + 64 * DPROJ;
    #pragma unroll
    for (int r = 0; r < 4; ++r) {
        cp0[(long)r * DPROJ]      = acc00[r];
        cp0[(long)r * DPROJ + 16] = acc01[r];
        cp1[(long)r * DPROJ]      = acc10[r];
        cp1[(long)r * DPROJ + 16] = acc11[r];
    }
}

// ---------------- cooperative dataflow scan + fused out-projection ----------------
// Epoch-tagged single-hop handoffs: every inter-wg word is a self-describing
// 64-bit atomic {payload32, epoch32}; consumers poll the DATA until the epoch
// matches (1 agent-hop instead of store->drain->flag->poll->load = 3 hops).
//   B->A: tagged[2][16][1024] u64 {2xbf16, epoch} depth-2 ring.
//   A->B: rawP[2][8][16][2336] u64 {f32 K-partial per wave, epoch} -- A waves are
//         fully independent (no LDS reduce/barriers); B sums the 8 partials.
//   msum: [2][16][32] u64 {f32, epoch}, loaded by 32 lanes/wave + shuffle reduce.
// Ring WAR safety is transitive through data dependences (MFMA fragments span the
// wave, state s chains across steps); no wg can lap a reader of a slot it reuses.
__global__ __launch_bounds__(NTHR, 1) void scan_kernel(
    const float* __restrict__ zx,             // [16][512][4384]
    unsigned long long* __restrict__ rawP,    // [2][8][16][2336] {f32,epoch}
    unsigned short* __restrict__ ghist,       // [513][16][2048] bf16 compact (out-proj)
    unsigned long long* __restrict__ tagged,  // [2][16][1024] {2xbf16,epoch}
    unsigned long long* __restrict__ msum,    // [2][16][32] {f32,epoch}
    unsigned* __restrict__ bar,               // 128 end flags (stride 32)
    const short* __restrict__ wall,           // [3360][2048] bf16
    float* __restrict__ scale_hist,           // [16][512]
    const float* __restrict__ dt_bias, const float* __restrict__ A_log,
    const float* __restrict__ D_param, const float* __restrict__ norm_w,
    const float* __restrict__ conv_w, const float* __restrict__ conv_b,
    float* __restrict__ out)                  // [16][512][1024]
{
    const int w = blockIdx.x, tid = threadIdx.x;
    const int lane = tid & 63, wv = tid >> 6;

    __shared__ float bc_lds[2][128];
    __shared__ float ypart[4][64];

    // ---- Phase A config ----
    const bool doA = (w < AWG);
    const int colr = lane & 15, q = lane >> 4;

    // weights register-resident: 16 x short8 = 64 VGPRs
    short8 wr0[8], wr1[8];
    if (doA) {
        const short* wp0 = wall + ((long)((2 * w    ) * 16 + colr) * KD + wv * 256 + q * 8);
        const short* wp1 = wall + ((long)((2 * w + 1) * 16 + colr) * KD + wv * 256 + q * 8);
        #pragma unroll
        for (int ks = 0; ks < 8; ++ks) {
            wr0[ks] = *(const short8*)(wp0 + ks * 32);
            wr1[ks] = *(const short8*)(wp1 + ks * 32);
        }
    }

    // ---- Phase B config ----
    const int b = w >> 3;
    const int j = w & 7;
    const int h = j * 4 + (wv >> 1);
    const int half = wv & 1;
    float s[64];
    #pragma unroll
    for (int i = 0; i < 64; ++i) s[i] = 0.f;
    const float Aneg = -__expf(A_log[h]);
    const float dtb  = dt_bias[h];
    const float Dp   = D_param[h];
    const float nw   = norm_w[h * 64 + lane];
    const int cx = h * 64 + lane;                  // x conv channel (= z col)
    const float4 cwx = *(const float4*)(conv_w + cx * 4);
    const float cbx = conv_b[cx];
    const int bcw = tid >> 7, bcn = tid & 127;     // bc staging slot (tid<256)
    const int cbc = 2048 + bcw * 128 + bcn;        // B/C conv channel
    float4 cwbc = {0.f,0.f,0.f,0.f}; float cbbc = 0.f;
    if (tid < 256) { cwbc = *(const float4*)(conv_w + cbc * 4); cbbc = conv_b[cbc]; }
    float xh1 = 0.f, xh2 = 0.f, xh3 = 0.f, bh1 = 0.f, bh2 = 0.f, bh3 = 0.f;

    for (int t = 0; t < LQ; ++t) {
        const unsigned eR = (unsigned)(t + 1);
        // ---- prefetch step-t streams (in flight during spins) ----
        const long zr = ((long)b * LQ + t) * DPROJ;
        float xq  = zx[zr + 2048 + cx];
        float zq  = zx[zr + cx];
        float dzq = zx[zr + 4352 + h];
        float bq = 0.f;
        if (tid < 256) bq = zx[zr + 2048 + cbc];

        // ---- Phase A: poll tagged ghist, MFMA, store per-wave K-partials ----
        if (doA) {
            const unsigned et = (unsigned)t;
            const unsigned long long* tg = tagged + (long)(t & 1) * TAG_SLOT
                                           + colr * 1024 + wv * 128 + q * 4;
            // parallel sentinel pre-poll: one word per 128B line (8 lines/lane)
            while (true) {
                unsigned bad = 0;
                #pragma unroll
                for (int ks = 0; ks < 8; ++ks)
                    bad |= hie(ld64(tg + ks * 16 + 3)) ^ et;
                if (!__any(bad != 0u)) break;
            }
            unsigned long long aw[32];
            #pragma unroll
            for (int ks = 0; ks < 8; ++ks) {
                #pragma unroll
                for (int c = 0; c < 4; ++c)
                    aw[ks * 4 + c] = ld64(tg + ks * 16 + c);
            }
            while (true) {                     // guarantee loop (rarely iterates)
                unsigned bad = 0;
                #pragma unroll
                for (int i = 0; i < 32; ++i) bad |= hie(aw[i]) ^ et;
                if (!__any(bad != 0u)) break;
                #pragma unroll
                for (int ks = 0; ks < 8; ++ks) {
                    #pragma unroll
                    for (int c = 0; c < 4; ++c)
                        if (hie(aw[ks * 4 + c]) != et)
                            aw[ks * 4 + c] = ld64(tg + ks * 16 + c);
                }
            }
            floatx4 acc0 = {0.f,0.f,0.f,0.f}, acc1 = {0.f,0.f,0.f,0.f};
            #pragma unroll
            for (int ks = 0; ks < 8; ++ks) {
                union { unsigned u[4]; short8 s8; } af;
                af.u[0] = (unsigned)aw[ks*4+0]; af.u[1] = (unsigned)aw[ks*4+1];
                af.u[2] = (unsigned)aw[ks*4+2]; af.u[3] = (unsigned)aw[ks*4+3];
                acc0 = __builtin_amdgcn_mfma_f32_16x16x32_bf16(af.s8, wr0[ks], acc0, 0, 0, 0);
                acc1 = __builtin_amdgcn_mfma_f32_16x16x32_bf16(af.s8, wr1[ks], acc1, 0, 0, 0);
            }
            unsigned long long* rp = rawP + (long)(t & 1) * RAWP_SLOT + wv * RAWP_WSTRIDE;
            const int c0 = 32 * w + colr;
            #pragma unroll
            for (int r = 0; r < 4; ++r) {
                const int bb = q * 4 + r;
                st64(rp + bb * 2336 + c0,      packf(acc0[r], eR));
                st64(rp + bb * 2336 + c0 + 16, packf(acc1[r], eR));
            }
        }

        // ---- Phase B: poll the 8 K-partials directly ----
        const unsigned long long* rbase = rawP + (long)(t & 1) * RAWP_SLOT + (long)b * 2336;
        unsigned long long xw[8];
        #pragma unroll
        for (int p = 0; p < 8; ++p) xw[p] = ld64(rbase + p * RAWP_WSTRIDE + cx);
        unsigned long long bw_[8];
        if (tid < 256) {
            #pragma unroll
            for (int p = 0; p < 8; ++p) bw_[p] = ld64(rbase + p * RAWP_WSTRIDE + cbc);
        }
        // msum (lanes 0-31, epoch t) and dtrr partials (lanes 32-39, epoch t+1)
        float mv = 0.f, dvp = 0.f;
        if (lane < 32) {
            const unsigned long long* mp = msum + ((t + 1) & 1) * MSUM_SLOT + b * 32 + lane;
            unsigned long long wd = ld64(mp);
            while (hie(wd) != (unsigned)t) wd = ld64(mp);
            mv = lof(wd);
        } else if (lane < 40) {
            const unsigned long long* dp = rbase + (lane - 32) * RAWP_WSTRIDE + 2304 + h;
            unsigned long long wd = ld64(dp);
            while (hie(wd) != eR) wd = ld64(dp);
            dvp = lof(wd);
        }
        float msv = mv;
        #pragma unroll
        for (int off = 32; off; off >>= 1) msv += __shfl_xor(msv, off, 64);
        float dsum = dvp;
        dsum += __shfl_xor(dsum, 1, 64);
        dsum += __shfl_xor(dsum, 2, 64);
        dsum += __shfl_xor(dsum, 4, 64);
        const float dtrr = __shfl(dsum, 32, 64);
        const float rs = rsqrtf(msv * (1.f / 2048.f) + 1e-5f);
        if (j == 0 && tid == 0 && t >= 1)
            __hip_atomic_store(scale_hist + b * LQ + (t - 1), rs,
                               __ATOMIC_RELAXED, __HIP_MEMORY_SCOPE_AGENT);
        // xr: fix-poll then sum
        while (true) {
            unsigned bad = 0;
            #pragma unroll
            for (int p = 0; p < 8; ++p) bad |= hie(xw[p]) ^ eR;
            if (!__any(bad != 0u)) break;
            #pragma unroll
            for (int p = 0; p < 8; ++p)
                if (hie(xw[p]) != eR) xw[p] = ld64(rbase + p * RAWP_WSTRIDE + cx);
        }
        float xr = 0.f;
        #pragma unroll
        for (int p = 0; p < 8; ++p) xr += lof(xw[p]);
        if (tid < 256) {
            while (true) {
                unsigned bad = 0;
                #pragma unroll
                for (int p = 0; p < 8; ++p) bad |= hie(bw_[p]) ^ eR;
                if (!__any(bad != 0u)) break;
                #pragma unroll
                for (int p = 0; p < 8; ++p)
                    if (hie(bw_[p]) != eR) bw_[p] = ld64(rbase + p * RAWP_WSTRIDE + cbc);
            }
            float bcval = 0.f;
            #pragma unroll
            for (int p = 0; p < 8; ++p) bcval += lof(bw_[p]);
            float pre = cbbc + bh3 * cwbc.x + bh2 * cwbc.y + bh1 * cwbc.z + bq * cwbc.w;
            bc_lds[bcw][bcn] = siluf(pre + rs * bcval);
            bh3 = bh2; bh2 = bh1; bh1 = bq;
        }
        float xpre = cbx + xh3 * cwx.x + xh2 * cwx.y + xh1 * cwx.z + xq * cwx.w;
        xh3 = xh2; xh2 = xh1; xh1 = xq;
        float xv = siluf(xpre + rs * xr);
        float dt = softplusf(siluf(dzq + rs * dtrr) + dtb);
        float dA = __expf(dt * Aneg);
        float zg = siluf(zq);
        __syncthreads();       // join: bc_lds staged by waves 0-3, read by all

        float dtx = dt * xv, yac = 0.f;
        const floatx4* Bp = (const floatx4*)&bc_lds[0][half * 64];
        const floatx4* Cp = (const floatx4*)&bc_lds[1][half * 64];
        #pragma unroll
        for (int i = 0; i < 16; ++i) {
            floatx4 b4 = Bp[i], c4 = Cp[i];
            s[4*i+0] = s[4*i+0] * dA + dtx * b4.x; yac += s[4*i+0] * c4.x;
            s[4*i+1] = s[4*i+1] * dA + dtx * b4.y; yac += s[4*i+1] * c4.y;
            s[4*i+2] = s[4*i+2] * dA + dtx * b4.z; yac += s[4*i+2] * c4.z;
            s[4*i+3] = s[4*i+3] * dA + dtx * b4.w; yac += s[4*i+3] * c4.w;
        }
        if (half) ypart[wv >> 1][lane] = yac;
        __syncthreads();       // ypart barrier (also protects bc_lds WAR next step)
        if (!half) {
            float y = yac + ypart[wv >> 1][lane] + Dp * xv;
            float g = y * zg;
            unsigned gb = (unsigned)f2bf(g * nw);
            unsigned up = __shfl_down(gb, 1);
            if (!(lane & 1)) {
                const long pidx = ((long)b * 1024 + ((h * 64 + lane) >> 1));
                unsigned packed = gb | (up << 16);
                __hip_atomic_store((unsigned*)ghist + ((long)(t + 1) * 16384 + pidx), packed,
                                   __ATOMIC_RELAXED, __HIP_MEMORY_SCOPE_AGENT);
                st64(tagged + ((long)((t + 1) & 1) * TAG_SLOT + pidx), packu(packed, eR));
            }
            float sq = g * g;
            #pragma unroll
            for (int off = 32; off; off >>= 1) sq += __shfl_xor(sq, off, 64);
            if (lane == 0)
                st64(msum + ((t & 1) * MSUM_SLOT + b * 32 + j * 4 + (wv >> 1)), packf(sq, eR));
        }
        // no trailing barrier; no drains, no flags
    }

    // ======== post-loop join + fused out-projection (all 128 wgs) ========
    asm volatile("s_waitcnt vmcnt(0)" ::: "memory");
    __syncthreads();
    if (tid == 0)
        __hip_atomic_store(bar + w * 32, 1u, __ATOMIC_RELAXED, __HIP_MEMORY_SCOPE_AGENT);
    if (tid < 128) {
        const unsigned* fp = bar + tid * 32;
        while (__hip_atomic_load(fp, __ATOMIC_RELAXED, __HIP_MEMORY_SCOPE_AGENT) < 1u) {}
    }
    __syncthreads();
    {
        const int vb = w * 2 + (tid >> 8);    // virtual 256-thread block: 0..255
        const int vt = tid & 255;
        const int vwv = vt >> 6, vlane = vt & 63;
        const int vcolr = vlane & 15, vq = vlane >> 4;   // vcolr = batch row of A
        const unsigned long long* gq2 = (const unsigned long long*)ghist;
        for (int it = 0; it < 8; ++it) {
            const int idx = vb * 8 + it;       // 0..2047 = (t, n-block)
            const int tt = idx >> 2;
            const int n0 = (idx & 3) * 256 + vwv * 64;
            const long ab = (long)(tt + 1) * 8192 + vcolr * 512 + vq * 2;
            const short* bp = wall + ((long)(2336 + n0 + vcolr) * KD + vq * 8);
            floatx4 acc0 = {0.f,0.f,0.f,0.f}, acc1 = {0.f,0.f,0.f,0.f};
            floatx4 acc2 = {0.f,0.f,0.f,0.f}, acc3 = {0.f,0.f,0.f,0.f};
            #pragma unroll 4
            for (int kb = 0; kb < 64; ++kb) {
                unsigned long long a0 = ld64(gq2 + ab + kb * 8);
                unsigned long long a1 = ld64(gq2 + ab + kb * 8 + 1);
                union { unsigned long long u[2]; short8 s8; } af;
                af.u[0] = a0; af.u[1] = a1;
                const short* bk = bp + kb * 32;
                acc0 = __builtin_amdgcn_mfma_f32_16x16x32_bf16(af.s8, *(const short8*)(bk),           acc0, 0, 0, 0);
                acc1 = __builtin_amdgcn_mfma_f32_16x16x32_bf16(af.s8, *(const short8*)(bk + 16 * KD), acc1, 0, 0, 0);
                acc2 = __builtin_amdgcn_mfma_f32_16x16x32_bf16(af.s8, *(const short8*)(bk + 32 * KD), acc2, 0, 0, 0);
                acc3 = __builtin_amdgcn_mfma_f32_16x16x32_bf16(af.s8, *(const short8*)(bk + 48 * KD), acc3, 0, 0, 0);
            }
            #pragma unroll
            for (int r = 0; r < 4; ++r) {
                const int bb = vq * 4 + r;     // batch
                float sc;
                if (tt < LQ - 1) {
                    sc = __hip_atomic_load(scale_hist + bb * LQ + tt,
                                           __ATOMIC_RELAXED, __HIP_MEMORY_SCOPE_AGENT);
                } else {
                    // rs(511): msum slot (511&1)=1, epoch 512 (visible post-join)
                    float msv = 0.f;
                    #pragma unroll
                    for (int k = 0; k < 32; ++k)
                        msv += lof(ld64(msum + 1 * MSUM_SLOT + bb * 32 + k));
                    sc = rsqrtf(msv * (1.f / 2048.f) + 1e-5f);
                }
                float* op = out + ((long)bb * LQ + tt) * DM + n0 + vcolr;
                op[0]  = acc0[r] * sc;
                op[16] = acc1[r] * sc;
                op[32] = acc2[r] * sc;
                op[48] = acc3[r] * sc;
            }
        }
    }
}

extern "C" void kernel_launch(void* const* d_in, const int* in_sizes, int n_in,
                              void* d_out, int out_size, void* d_ws, size_t ws_size,
                              hipStream_t stream) {
    const float* u       = (const float*)d_in[0];
    const float* W_in    = (const float*)d_in[1];
    const float* conv_w  = (const float*)d_in[2];
    const float* conv_b  = (const float*)d_in[3];
    const float* W_rxbc  = (const float*)d_in[4];
    const float* W_rdt   = (const float*)d_in[5];
    const float* dt_bias = (const float*)d_in[6];
    const float* A_log   = (const float*)d_in[7];
    const float* D_param = (const float*)d_in[8];
    const float* norm_w  = (const float*)d_in[9];
    const float* W_out   = (const float*)d_in[10];
    float* out = (float*)d_out;

    char* ws = (char*)d_ws;
    size_t off = 0;
    auto alloc = [&](size_t bytes) -> void* {
        void* p = ws + off; off += (bytes + 255) & ~(size_t)255; return p;
    };
    float* zx            = (float*)alloc((size_t)BQ * LQ * DPROJ * 4);        // 143.7 MB
    unsigned short* u_bf = (unsigned short*)alloc((size_t)BQ * LQ * DM * 2);  // reused as wall
    unsigned short* w_bf = (unsigned short*)alloc((size_t)DPROJ * DM * 2);
    unsigned short* gh   = (unsigned short*)alloc((size_t)(LQ + 1) * BQ * KD * 2);  // 33.6 MB
    // contiguous zero-span: [tagged | msum | rawP | bar] (all sizes 256-aligned)
    unsigned long long* tagged = (unsigned long long*)alloc((size_t)2 * TAG_SLOT * 8);   // 256 KB
    unsigned long long* msum   = (unsigned long long*)alloc((size_t)2 * MSUM_SLOT * 8);  // 8 KB
    unsigned long long* rawP   = (unsigned long long*)alloc((size_t)2 * RAWP_SLOT * 8);  // 4.78 MB
    unsigned* bar        = (unsigned*)alloc(128 * 32 * 4);                               // 16 KB
    float* scale_hist    = (float*)alloc((size_t)BQ * LQ * 4);

    const long zero_u32 = ((size_t)2 * TAG_SLOT * 8 + (size_t)2 * MSUM_SLOT * 8
                           + (size_t)2 * RAWP_SLOT * 8 + 128 * 32 * 4) / 4;
    setup_zero_kernel<<<2048, 256, 0, stream>>>((unsigned*)tagged, zero_u32);

    { int n = BQ * LQ * DM; cvt_bf16_kernel<<<(n + 255) / 256, 256, 0, stream>>>(u, u_bf, n); }
    { int n = DPROJ * DM;   cvt_bf16_kernel<<<(n + 255) / 256, 256, 0, stream>>>(W_in, w_bf, n); }
    gemm_inproj_kernel<<<dim3(BQ * LQ / 128, DPROJ / 32), 256, 0, stream>>>(
        (const short*)u_bf, (const short*)w_bf, zx);
    unsigned short* wall = u_bf;   // dead after GEMM; reuse for packed scan weights
    { long n = 3360L * KD;
      pack_weights_kernel<<<(int)((n + 255) / 256), 256, 0, stream>>>(W_rxbc, W_rdt, W_out, wall); }

    void* args[] = { &zx, &rawP, &gh, &tagged, &msum, &bar, &wall, &scale_hist,
                     &dt_bias, &A_log, &D_param, &norm_w, &conv_w, &conv_b, &out };
    hipLaunchCooperativeKernel((void*)scan_kernel, dim3(NWG), dim3(NTHR), args, 0, stream);
}

// Round 5
// 5753.630 us; speedup vs baseline: 2.3850x; 2.3850x over previous
//
#include <hip/hip_runtime.h>

typedef __attribute__((ext_vector_type(8))) short short8;
typedef __attribute__((ext_vector_type(4))) float floatx4;

#define BQ 16
#define LQ 512
#define DM 1024
#define DPROJ 4384
#define RAWC 2336
#define KD 2048
#define NWG 128          // scan workgroups
#define NTHR 512         // threads per scan wg (8 waves)
#define AWG 73           // wgs running phase A: 73 x 32 cols = 2336

#define RAWT_SLOT 37376       // 16*2336 u64 (depth-2 ring)
#define MSUM_SLOT 512         // 16*32 u64 (depth-8 ring)

__device__ __forceinline__ float siluf(float x) { return x / (1.f + __expf(-x)); }
__device__ __forceinline__ float softplusf(float x) { return (x > 20.f) ? x : log1pf(__expf(x)); }
__device__ __forceinline__ unsigned short f2bf(float f) {
    union { float f; unsigned u; } v; v.f = f;
    unsigned r = v.u + 0x7FFFu + ((v.u >> 16) & 1u);
    return (unsigned short)(r >> 16);
}
__device__ __forceinline__ unsigned long long ld64(const unsigned long long* p) {
    return __hip_atomic_load(p, __ATOMIC_RELAXED, __HIP_MEMORY_SCOPE_AGENT);
}
__device__ __forceinline__ void st64(unsigned long long* p, unsigned long long v) {
    __hip_atomic_store(p, v, __ATOMIC_RELAXED, __HIP_MEMORY_SCOPE_AGENT);
}
__device__ __forceinline__ unsigned long long packf(float f, unsigned e) {
    union { float f; unsigned u; } v; v.f = f;
    return ((unsigned long long)e << 32) | v.u;
}
__device__ __forceinline__ float lof(unsigned long long w) {
    union { unsigned u; float f; } v; v.u = (unsigned)w; return v.f;
}
__device__ __forceinline__ unsigned hie(unsigned long long w) { return (unsigned)(w >> 32); }

// ---------------- fp32 -> bf16 conversion ----------------
__global__ void cvt_bf16_kernel(const float* __restrict__ s, unsigned short* __restrict__ d, int n) {
    int i = blockIdx.x * 256 + threadIdx.x;
    if (i < n) d[i] = f2bf(s[i]);
}

// ---------------- pack [W_rxbc|W_rdt|W_out] -> bf16 [3360][2048] ----------------
__global__ void pack_weights_kernel(const float* __restrict__ rxbc, const float* __restrict__ rdt,
                                    const float* __restrict__ wout, unsigned short* __restrict__ wall) {
    long i = (long)blockIdx.x * 256 + threadIdx.x;
    if (i >= 3360L * KD) return;
    int c = (int)(i >> 11), k = (int)(i & 2047);
    const float* src = (c < 2304) ? rxbc + (long)c * KD + k
                     : (c < 2336) ? rdt + (long)(c - 2304) * KD + k
                     :              wout + (long)(c - 2336) * KD + k;
    wall[i] = f2bf(*src);
}

// ---------------- zero init (grid-stride; NO hipMemsetAsync in capture) ----------
__global__ void setup_zero_kernel(unsigned* __restrict__ z, long nz, unsigned* __restrict__ gh0) {
    long i = (long)blockIdx.x * 256 + threadIdx.x;
    const long stride = (long)gridDim.x * 256;
    for (long k = i; k < nz; k += stride) z[k] = 0u;
    if (i < 16384) gh0[i] = 0u;   // ghist slot 0: 16x2048 bf16 = 16384 u32
}

// ---------------- in_proj GEMM: 128x32 blocks ----------
__global__ __launch_bounds__(256) void gemm_inproj_kernel(const short* __restrict__ A,
                                                          const short* __restrict__ Bw,
                                                          float* __restrict__ C) {
    const int lane = threadIdx.x & 63, wave = threadIdx.x >> 6;
    const int row = lane & 15, q = lane >> 4;
    const long m0 = (long)blockIdx.x * 128 + wave * 16;
    const long n0 = (long)blockIdx.y * 32;
    const short* ap0 = A + (m0 + row) * DM + q * 8;
    const short* ap1 = ap0 + 64 * DM;
    const short* bp0 = Bw + (n0 + row) * DM + q * 8;
    const short* bp1 = bp0 + 16 * DM;
    floatx4 acc00 = {0.f,0.f,0.f,0.f}, acc01 = {0.f,0.f,0.f,0.f};
    floatx4 acc10 = {0.f,0.f,0.f,0.f}, acc11 = {0.f,0.f,0.f,0.f};
    for (int k = 0; k < DM; k += 32) {
        short8 a0 = *(const short8*)(ap0 + k);
        short8 a1 = *(const short8*)(ap1 + k);
        short8 b0 = *(const short8*)(bp0 + k);
        short8 b1 = *(const short8*)(bp1 + k);
        acc00 = __builtin_amdgcn_mfma_f32_16x16x32_bf16(a0, b0, acc00, 0, 0, 0);
        acc01 = __builtin_amdgcn_mfma_f32_16x16x32_bf16(a0, b1, acc01, 0, 0, 0);
        acc10 = __builtin_amdgcn_mfma_f32_16x16x32_bf16(a1, b0, acc10, 0, 0, 0);
        acc11 = __builtin_amdgcn_mfma_f32_16x16x32_bf16(a1, b1, acc11, 0, 0, 0);
    }
    float* cp0 = C + (m0 + q * 4) * DPROJ + n0 + row;
    float* cp1 = cp0 + 64 * DPROJ;
    #pragma unroll
    for (int r = 0; r < 4; ++r) {
        cp0[(long)r * DPROJ]      = acc00[r];
        cp0[(long)r * DPROJ + 16] = acc01[r];
        cp1[(long)r * DPROJ]      = acc10[r];
        cp1[(long)r * DPROJ + 16] = acc11[r];
    }
}

// ---------------- cooperative dataflow scan + fused out-projection ----------------
// Hybrid protocol (r4 post-mortem: hop VOLUME matters, not just hop count):
//   A->B single-hop at COMPACT volume: A keeps its intra-wg LDS reduce, stores
//     rawT[2][16][2336] u64 {f32,epoch} (300KB/step); B polls exactly the words
//     it consumes (1/thread x, 1/thread B/C, 1 broadcast dt). No aflag, no A drain.
//   B->A stays flag-based (r2, proven cheap): ghist u32 compact + per-wavepair
//     vmcnt drain + bflagF; A spins 1 flag/lane then bulk-loads ghist.
//   msum: u64 {f32,epoch} depth-8 ring (depth-2 + epoch check could deadlock on
//     skew). msum poll also transitively closes the rawT depth-2 WAR window.
__global__ __launch_bounds__(NTHR, 1) void scan_kernel(
    const float* __restrict__ zx,             // [16][512][4384]
    unsigned long long* __restrict__ rawT,    // [2][16][2336] {f32,epoch}
    unsigned short* __restrict__ ghist,       // [513][16][2048] bf16
    unsigned long long* __restrict__ msum,    // [8][16][32] {f32,epoch}
    unsigned* __restrict__ bar,               // 512 bflagF (stride 32)
    const short* __restrict__ wall,           // [3360][2048] bf16
    float* __restrict__ scale_hist,           // [16][512]
    const float* __restrict__ dt_bias, const float* __restrict__ A_log,
    const float* __restrict__ D_param, const float* __restrict__ norm_w,
    const float* __restrict__ conv_w, const float* __restrict__ conv_b,
    float* __restrict__ out)                  // [16][512][1024]
{
    const int w = blockIdx.x, tid = threadIdx.x;
    const int lane = tid & 63, wv = tid >> 6;

    __shared__ float redu[2][8][16][16];   // 16 KB
    __shared__ float bc_lds[2][128];
    __shared__ float ypart[4][64];

    // ---- Phase A config ----
    const bool doA = (w < AWG);
    const int colr = lane & 15, q = lane >> 4;
    const unsigned long long* gq = (const unsigned long long*)ghist;  // slot stride 8192 u64
    const int abase = colr * 512 + wv * 64 + q * 2;
    const int r_tl = tid >> 8, r_idx = tid & 255, r_orow = r_idx >> 4, r_col = r_idx & 15;
    // A-wave spin: lane l waits bflagF[wg=(l>>2)*8+wv][wp=l&3] >= t (union = its 16 producers)
    const unsigned* aspin = bar + ((((lane >> 2) * 8 + wv) * 4) + (lane & 3)) * 32;

    // weights register-resident: 16 x short8 = 64 VGPRs
    short8 wr0[8], wr1[8];
    if (doA) {
        const short* wp0 = wall + ((long)((2 * w    ) * 16 + colr) * KD + wv * 256 + q * 8);
        const short* wp1 = wall + ((long)((2 * w + 1) * 16 + colr) * KD + wv * 256 + q * 8);
        #pragma unroll
        for (int ks = 0; ks < 8; ++ks) {
            wr0[ks] = *(const short8*)(wp0 + ks * 32);
            wr1[ks] = *(const short8*)(wp1 + ks * 32);
        }
    }

    // ---- Phase B config ----
    const int b = w >> 3;
    const int j = w & 7;
    const int h = j * 4 + (wv >> 1);
    const int half = wv & 1;
    float s[64];
    #pragma unroll
    for (int i = 0; i < 64; ++i) s[i] = 0.f;
    const float Aneg = -__expf(A_log[h]);
    const float dtb  = dt_bias[h];
    const float Dp   = D_param[h];
    const float nw   = norm_w[h * 64 + lane];
    const int cx = h * 64 + lane;                  // x conv channel (= z col)
    const float4 cwx = *(const float4*)(conv_w + cx * 4);
    const float cbx = conv_b[cx];
    const int bcw = tid >> 7, bcn = tid & 127;     // bc staging slot (tid<256)
    const int cbc = 2048 + bcw * 128 + bcn;        // B/C conv channel
    float4 cwbc = {0.f,0.f,0.f,0.f}; float cbbc = 0.f;
    if (tid < 256) { cwbc = *(const float4*)(conv_w + cbc * 4); cbbc = conv_b[cbc]; }
    float xh1 = 0.f, xh2 = 0.f, xh3 = 0.f, bh1 = 0.f, bh2 = 0.f, bh3 = 0.f;

    for (int t = 0; t < LQ; ++t) {
        const unsigned eR = (unsigned)(t + 1);
        // ---- prefetch step-t streams (in flight during spins) ----
        const long zr = ((long)b * LQ + t) * DPROJ;
        float xq  = zx[zr + 2048 + cx];
        float zq  = zx[zr + cx];
        float dzq = zx[zr + 4352 + h];
        float bq = 0.f;
        if (tid < 256) bq = zx[zr + 2048 + cbc];

        // ---- Phase A: flag spin -> ghist load -> MFMA -> LDS reduce -> tagged store
        if (doA) {
            while (__hip_atomic_load(aspin, __ATOMIC_RELAXED, __HIP_MEMORY_SCOPE_AGENT)
                   < (unsigned)t) {}
            unsigned long long ar[16];
            const long gb0 = (long)t * 8192 + abase;
            #pragma unroll
            for (int ks = 0; ks < 8; ++ks) {
                ar[2 * ks]     = ld64(gq + gb0 + ks * 8);
                ar[2 * ks + 1] = ld64(gq + gb0 + ks * 8 + 1);
            }
            floatx4 acc0 = {0.f,0.f,0.f,0.f}, acc1 = {0.f,0.f,0.f,0.f};
            #pragma unroll
            for (int ks = 0; ks < 8; ++ks) {
                union { unsigned long long u[2]; short8 s8; } af;
                af.u[0] = ar[2 * ks]; af.u[1] = ar[2 * ks + 1];
                acc0 = __builtin_amdgcn_mfma_f32_16x16x32_bf16(af.s8, wr0[ks], acc0, 0, 0, 0);
                acc1 = __builtin_amdgcn_mfma_f32_16x16x32_bf16(af.s8, wr1[ks], acc1, 0, 0, 0);
            }
            #pragma unroll
            for (int r = 0; r < 4; ++r) {
                redu[0][wv][q * 4 + r][colr] = acc0[r];
                redu[1][wv][q * 4 + r][colr] = acc1[r];
            }
            __syncthreads();           // redu write -> read
            float v = 0.f;
            #pragma unroll
            for (int kq = 0; kq < 8; ++kq) v += redu[r_tl][kq][r_orow][r_col];
            const int gc = (2 * w + r_tl) * 16 + r_col;
            st64(rawT + (long)(t & 1) * RAWT_SLOT + r_orow * 2336 + gc, packf(v, eR));
            // no drain, no flag; redu WAR is ordered by the B-phase join barrier
        }

        // ---- Phase B: poll exactly the tagged words this thread consumes ----
        const unsigned long long* rbase = rawT + (long)(t & 1) * RAWT_SLOT + (long)b * 2336;
        unsigned long long xw = ld64(rbase + cx);
        unsigned long long dw = ld64(rbase + 2304 + h);
        unsigned long long bw = 0;
        if (tid < 256) bw = ld64(rbase + cbc);
        // msum partials of step t-1: ring slot (t+7)&7, epoch t (lanes 0-31)
        float mv = 0.f;
        if (lane < 32) {
            const unsigned long long* mp = msum + ((t + 7) & 7) * MSUM_SLOT + b * 32 + lane;
            unsigned long long wd = ld64(mp);
            while (hie(wd) != (unsigned)t) wd = ld64(mp);
            mv = lof(wd);
        }
        float msv = mv;
        #pragma unroll
        for (int off = 32; off; off >>= 1) msv += __shfl_xor(msv, off, 64);
        const float rs = rsqrtf(msv * (1.f / 2048.f) + 1e-5f);
        if (j == 0 && tid == 0 && t >= 1)
            __hip_atomic_store(scale_hist + b * LQ + (t - 1), rs,
                               __ATOMIC_RELAXED, __HIP_MEMORY_SCOPE_AGENT);
        while (hie(xw) != eR) xw = ld64(rbase + cx);
        const float xr = lof(xw);
        while (hie(dw) != eR) dw = ld64(rbase + 2304 + h);
        const float dtrr = lof(dw);
        if (tid < 256) {
            while (hie(bw) != eR) bw = ld64(rbase + cbc);
            float bcval = lof(bw);
            float pre = cbbc + bh3 * cwbc.x + bh2 * cwbc.y + bh1 * cwbc.z + bq * cwbc.w;
            bc_lds[bcw][bcn] = siluf(pre + rs * bcval);
            bh3 = bh2; bh2 = bh1; bh1 = bq;
        }
        float xpre = cbx + xh3 * cwx.x + xh2 * cwx.y + xh1 * cwx.z + xq * cwx.w;
        xh3 = xh2; xh2 = xh1; xh1 = xq;
        float xv = siluf(xpre + rs * xr);
        float dt = softplusf(siluf(dzq + rs * dtrr) + dtb);
        float dA = __expf(dt * Aneg);
        float zg = siluf(zq);
        __syncthreads();       // join: bc_lds staged; also orders A's redu WAR

        float dtx = dt * xv, yac = 0.f;
        const floatx4* Bp = (const floatx4*)&bc_lds[0][half * 64];
        const floatx4* Cp = (const floatx4*)&bc_lds[1][half * 64];
        #pragma unroll
        for (int i = 0; i < 16; ++i) {
            floatx4 b4 = Bp[i], c4 = Cp[i];
            s[4*i+0] = s[4*i+0] * dA + dtx * b4.x; yac += s[4*i+0] * c4.x;
            s[4*i+1] = s[4*i+1] * dA + dtx * b4.y; yac += s[4*i+1] * c4.y;
            s[4*i+2] = s[4*i+2] * dA + dtx * b4.z; yac += s[4*i+2] * c4.z;
            s[4*i+3] = s[4*i+3] * dA + dtx * b4.w; yac += s[4*i+3] * c4.w;
        }
        if (half) ypart[wv >> 1][lane] = yac;
        __syncthreads();       // ypart barrier (also bc_lds WAR for next step)
        if (!half) {
            float y = yac + ypart[wv >> 1][lane] + Dp * xv;
            float g = y * zg;
            unsigned gb = (unsigned)f2bf(g * nw);
            unsigned up = __shfl_down(gb, 1);
            if (!(lane & 1))
                __hip_atomic_store((unsigned*)ghist + ((long)(t + 1) * 16384
                                   + ((b * KD + h * 64 + lane) >> 1)),
                                   gb | (up << 16), __ATOMIC_RELAXED, __HIP_MEMORY_SCOPE_AGENT);
            float sq = g * g;
            #pragma unroll
            for (int off = 32; off; off >>= 1) sq += __shfl_xor(sq, off, 64);
            if (lane == 0)
                st64(msum + ((t & 7) * MSUM_SLOT + b * 32 + j * 4 + (wv >> 1)), packf(sq, eR));
            asm volatile("s_waitcnt vmcnt(0)" ::: "memory");   // ghist drain (per wave)
            if (lane == 0)
                __hip_atomic_store(bar + (w * 4 + (wv >> 1)) * 32, (unsigned)(t + 1),
                                   __ATOMIC_RELAXED, __HIP_MEMORY_SCOPE_AGENT);
        }
        // no trailing barrier: odd waves proceed
    }

    // ======== post-loop join + fused out-projection (all 128 wgs) ========
    {
        const unsigned* fp = bar + tid * 32;   // 512 fine bflags, one per thread
        while (__hip_atomic_load(fp, __ATOMIC_RELAXED, __HIP_MEMORY_SCOPE_AGENT) < 512u) {}
    }
    __syncthreads();
    {
        const int vb = w * 2 + (tid >> 8);    // virtual 256-thread block: 0..255
        const int vt = tid & 255;
        const int vwv = vt >> 6, vlane = vt & 63;
        const int vcolr = vlane & 15, vq = vlane >> 4;   // vcolr = batch row of A
        const unsigned long long* gq2 = (const unsigned long long*)ghist;
        for (int it = 0; it < 8; ++it) {
            const int idx = vb * 8 + it;       // 0..2047 = (t, n-block)
            const int tt = idx >> 2;
            const int n0 = (idx & 3) * 256 + vwv * 64;
            const long ab = (long)(tt + 1) * 8192 + vcolr * 512 + vq * 2;
            const short* bp = wall + ((long)(2336 + n0 + vcolr) * KD + vq * 8);
            floatx4 acc0 = {0.f,0.f,0.f,0.f}, acc1 = {0.f,0.f,0.f,0.f};
            floatx4 acc2 = {0.f,0.f,0.f,0.f}, acc3 = {0.f,0.f,0.f,0.f};
            #pragma unroll 4
            for (int kb = 0; kb < 64; ++kb) {
                unsigned long long a0 = ld64(gq2 + ab + kb * 8);
                unsigned long long a1 = ld64(gq2 + ab + kb * 8 + 1);
                union { unsigned long long u[2]; short8 s8; } af;
                af.u[0] = a0; af.u[1] = a1;
                const short* bk = bp + kb * 32;
                acc0 = __builtin_amdgcn_mfma_f32_16x16x32_bf16(af.s8, *(const short8*)(bk),           acc0, 0, 0, 0);
                acc1 = __builtin_amdgcn_mfma_f32_16x16x32_bf16(af.s8, *(const short8*)(bk + 16 * KD), acc1, 0, 0, 0);
                acc2 = __builtin_amdgcn_mfma_f32_16x16x32_bf16(af.s8, *(const short8*)(bk + 32 * KD), acc2, 0, 0, 0);
                acc3 = __builtin_amdgcn_mfma_f32_16x16x32_bf16(af.s8, *(const short8*)(bk + 48 * KD), acc3, 0, 0, 0);
            }
            #pragma unroll
            for (int r = 0; r < 4; ++r) {
                const int bb = vq * 4 + r;     // batch
                float sc;
                if (tt < LQ - 1) {
                    sc = __hip_atomic_load(scale_hist + bb * LQ + tt,
                                           __ATOMIC_RELAXED, __HIP_MEMORY_SCOPE_AGENT);
                } else {
                    // rs(511): msum ring slot 511&7 = 7 (visible post-join)
                    float msv = 0.f;
                    #pragma unroll
                    for (int k = 0; k < 32; ++k)
                        msv += lof(ld64(msum + 7 * MSUM_SLOT + bb * 32 + k));
                    sc = rsqrtf(msv * (1.f / 2048.f) + 1e-5f);
                }
                float* op = out + ((long)bb * LQ + tt) * DM + n0 + vcolr;
                op[0]  = acc0[r] * sc;
                op[16] = acc1[r] * sc;
                op[32] = acc2[r] * sc;
                op[48] = acc3[r] * sc;
            }
        }
    }
}

extern "C" void kernel_launch(void* const* d_in, const int* in_sizes, int n_in,
                              void* d_out, int out_size, void* d_ws, size_t ws_size,
                              hipStream_t stream) {
    const float* u       = (const float*)d_in[0];
    const float* W_in    = (const float*)d_in[1];
    const float* conv_w  = (const float*)d_in[2];
    const float* conv_b  = (const float*)d_in[3];
    const float* W_rxbc  = (const float*)d_in[4];
    const float* W_rdt   = (const float*)d_in[5];
    const float* dt_bias = (const float*)d_in[6];
    const float* A_log   = (const float*)d_in[7];
    const float* D_param = (const float*)d_in[8];
    const float* norm_w  = (const float*)d_in[9];
    const float* W_out   = (const float*)d_in[10];
    float* out = (float*)d_out;

    char* ws = (char*)d_ws;
    size_t off = 0;
    auto alloc = [&](size_t bytes) -> void* {
        void* p = ws + off; off += (bytes + 255) & ~(size_t)255; return p;
    };
    float* zx            = (float*)alloc((size_t)BQ * LQ * DPROJ * 4);        // 143.7 MB
    unsigned short* u_bf = (unsigned short*)alloc((size_t)BQ * LQ * DM * 2);  // reused as wall
    unsigned short* w_bf = (unsigned short*)alloc((size_t)DPROJ * DM * 2);
    unsigned short* gh   = (unsigned short*)alloc((size_t)(LQ + 1) * BQ * KD * 2);  // 33.6 MB
    // contiguous zero-span: [rawT | msum | bar] (sizes are 256-multiples)
    unsigned long long* rawT = (unsigned long long*)alloc((size_t)2 * RAWT_SLOT * 8);  // 598 KB
    unsigned long long* msum = (unsigned long long*)alloc((size_t)8 * MSUM_SLOT * 8);  // 32 KB
    unsigned* bar        = (unsigned*)alloc(16384 * 4);                                // 64 KB
    float* scale_hist    = (float*)alloc((size_t)BQ * LQ * 4);

    const long zero_u32 = ((size_t)2 * RAWT_SLOT * 8 + (size_t)8 * MSUM_SLOT * 8
                           + (size_t)16384 * 4) / 4;
    setup_zero_kernel<<<680, 256, 0, stream>>>((unsigned*)rawT, zero_u32, (unsigned*)gh);

    { int n = BQ * LQ * DM; cvt_bf16_kernel<<<(n + 255) / 256, 256, 0, stream>>>(u, u_bf, n); }
    { int n = DPROJ * DM;   cvt_bf16_kernel<<<(n + 255) / 256, 256, 0, stream>>>(W_in, w_bf, n); }
    gemm_inproj_kernel<<<dim3(BQ * LQ / 128, DPROJ / 32), 256, 0, stream>>>(
        (const short*)u_bf, (const short*)w_bf, zx);
    unsigned short* wall = u_bf;   // dead after GEMM; reuse for packed scan weights
    { long n = 3360L * KD;
      pack_weights_kernel<<<(int)((n + 255) / 256), 256, 0, stream>>>(W_rxbc, W_rdt, W_out, wall); }

    void* args[] = { &zx, &rawT, &gh, &msum, &bar, &wall, &scale_hist,
                     &dt_bias, &A_log, &D_param, &norm_w, &conv_w, &conv_b, &out };
    hipLaunchCooperativeKernel((void*)scan_kernel, dim3(NWG), dim3(NTHR), args, 0, stream);
}